// Round 5
// baseline (515.484 us; speedup 1.0000x reference)
//
#include <hip/hip_runtime.h>

typedef __attribute__((ext_vector_type(8))) short bf16x8;
typedef __attribute__((ext_vector_type(4))) float f32x4;

// RNE float -> bf16
__device__ __forceinline__ unsigned short f2bf(float f) {
    union { float f; unsigned int u; } v; v.f = f;
    unsigned int r = v.u + 0x7FFFu + ((v.u >> 16) & 1u);
    return (unsigned short)(r >> 16);
}
__device__ __forceinline__ float bf2f(unsigned short h) {
    union { unsigned int u; float f; } v; v.u = (unsigned int)h << 16;
    return v.f;
}

// ---------------- counting-sort machinery ----------------
__global__ void hist_k(const int* __restrict__ dst, unsigned* __restrict__ counts, int E) {
    for (int i = blockIdx.x * blockDim.x + threadIdx.x; i < E; i += gridDim.x * blockDim.x)
        atomicAdd(&counts[dst[i]], 1u);
}

__global__ __launch_bounds__(1024)
void scan_k(const unsigned* __restrict__ counts, unsigned* __restrict__ cursor, int N) {
    __shared__ unsigned part[1024];
    const int t = threadIdx.x;
    const int chunk = (N + 1023) >> 10;
    const int lo = t * chunk, hi = min(lo + chunk, N);
    unsigned s = 0;
    for (int i = lo; i < hi; ++i) s += counts[i];
    part[t] = s;
    __syncthreads();
    for (int off = 1; off < 1024; off <<= 1) {
        unsigned v = (t >= off) ? part[t - off] : 0u;
        __syncthreads();
        part[t] += v;
        __syncthreads();
    }
    unsigned run = t ? part[t - 1] : 0u;
    for (int i = lo; i < hi; ++i) { cursor[i] = run; run += counts[i]; }
}

// pos[i] = sorted position of edge i (coalesced write; cursor ends at start+count)
__global__ void scatter_k(const int* __restrict__ dst, unsigned* __restrict__ cursor,
                          unsigned* __restrict__ pos, int E) {
    for (int i = blockIdx.x * blockDim.x + threadIdx.x; i < E; i += gridDim.x * blockDim.x)
        pos[i] = atomicAdd(&cursor[dst[i]], 1u);
}

// ---------------- Phase A: edge MLP, natural order, barrier/LDS-free ----------------
// One wave = 16 edges. Swapped MFMA: acc = mfma(Wfrag, datafrag) -> lane holds
// edge (lane&15), features f*16 + (lane>>4)*4 + r. Y row written at pos[e]
// (CSR order) as bf16, so Phase B reads contiguously.
__global__ __launch_bounds__(256, 4)
void edge_mlp(const float* __restrict__ H, const float* __restrict__ Xe,
              const int* __restrict__ src, const unsigned* __restrict__ pos,
              const float* __restrict__ W, const float* __restrict__ bias,
              unsigned short* __restrict__ Y, int E)
{
    const int t = threadIdx.x, lane = t & 63;
    const int lrow = lane & 15, kc = lane >> 4, lko = kc * 8, fo = kc * 4;
    const long long gw = (long long)(blockIdx.x * blockDim.x + t) >> 6;
    const long long nw = (long long)(gridDim.x * blockDim.x) >> 6;
    const long long ngrp = ((long long)E + 15) >> 4;

    // W fragments (A-operand): lane holds W[f*16+lrow][ks*32+lko+i]
    bf16x8 wfrag[4][4];
#pragma unroll
    for (int f = 0; f < 4; ++f)
#pragma unroll
        for (int ks = 0; ks < 4; ++ks) {
            const float* wp = W + (f * 16 + lrow) * 128 + ks * 32 + lko;
            bf16x8 v;
#pragma unroll
            for (int i = 0; i < 8; ++i) ((unsigned short*)&v)[i] = f2bf(wp[i]);
            wfrag[f][ks] = v;
        }
    f32x4 bia[4];
#pragma unroll
    for (int f = 0; f < 4; ++f) bia[f] = *(const f32x4*)(bias + f * 16 + fo);

    for (long long g = gw; g < ngrp; g += nw) {
        const long long el = g * 16 + lrow;      // this lane's edge
        const bool ok = el < (long long)E;
        const int      sv = ok ? src[el] : 0;
        const unsigned pp = ok ? pos[el] : 0u;
        const float* hp = H  + (long long)sv * 64;
        const float* xp = Xe + el * 64;

        // data fragments (B-operand): k = ks*32 + kc*8 + i over [H_src | Xe_e]
        bf16x8 dfrag[4];
#pragma unroll
        for (int ks = 0; ks < 4; ++ks) {
            const float* p = (ks < 2) ? (hp + ks * 32 + lko)
                                      : (xp + (ks - 2) * 32 + lko);
            float4 a = make_float4(0.f, 0.f, 0.f, 0.f), b = a;
            if (ok) { a = *(const float4*)p; b = *(const float4*)(p + 4); }
            bf16x8 v;
            ((unsigned short*)&v)[0] = f2bf(a.x); ((unsigned short*)&v)[1] = f2bf(a.y);
            ((unsigned short*)&v)[2] = f2bf(a.z); ((unsigned short*)&v)[3] = f2bf(a.w);
            ((unsigned short*)&v)[4] = f2bf(b.x); ((unsigned short*)&v)[5] = f2bf(b.y);
            ((unsigned short*)&v)[6] = f2bf(b.z); ((unsigned short*)&v)[7] = f2bf(b.w);
            dfrag[ks] = v;
        }

        f32x4 acc[4] = {{0,0,0,0},{0,0,0,0},{0,0,0,0},{0,0,0,0}};
#pragma unroll
        for (int ks = 0; ks < 4; ++ks)
#pragma unroll
            for (int f = 0; f < 4; ++f)
                acc[f] = __builtin_amdgcn_mfma_f32_16x16x32_bf16(wfrag[f][ks], dfrag[ks], acc[f], 0, 0, 0);

        if (ok) {
            unsigned short* yp = Y + (long long)pp * 64 + fo;
#pragma unroll
            for (int f = 0; f < 4; ++f) {
                ushort4 y;
                y.x = f2bf(fmaxf(acc[f][0] + bia[f][0], 0.f));
                y.y = f2bf(fmaxf(acc[f][1] + bia[f][1], 0.f));
                y.z = f2bf(fmaxf(acc[f][2] + bia[f][2], 0.f));
                y.w = f2bf(fmaxf(acc[f][3] + bia[f][3], 0.f));
                *(ushort4*)(yp + f * 16) = y;
            }
        }
    }
}

// ---------------- Phase B: wave-per-node segmented sum (contiguous Y rows) ----------------
__global__ __launch_bounds__(256)
void seg_reduce(const unsigned short* __restrict__ Y,
                const unsigned* __restrict__ counts, const unsigned* __restrict__ cursor,
                float* __restrict__ Z, int N)
{
    const int lane = threadIdx.x & 63;
    const int n = (blockIdx.x * blockDim.x + threadIdx.x) >> 6;
    if (n >= N) return;
    const unsigned e = cursor[n];
    const unsigned b = e - counts[n];
    float a0 = 0.f, a1 = 0.f, a2 = 0.f, a3 = 0.f;
    unsigned i = b;
    for (; i + 4 <= e; i += 4) {
        a0 += bf2f(Y[(long long)(i + 0) * 64 + lane]);
        a1 += bf2f(Y[(long long)(i + 1) * 64 + lane]);
        a2 += bf2f(Y[(long long)(i + 2) * 64 + lane]);
        a3 += bf2f(Y[(long long)(i + 3) * 64 + lane]);
    }
    for (; i < e; ++i) a0 += bf2f(Y[(long long)i * 64 + lane]);
    Z[(long long)n * 64 + lane] = (a0 + a1) + (a2 + a3);
}

// ------------- generic tiled MLP (R1, known-good): node pass + fallback -------------
__global__ __launch_bounds__(256)
void gnn_mlp(const float* __restrict__ A, const float* __restrict__ B2,
             const int* __restrict__ gidx, const int* __restrict__ sidx,
             const float* __restrict__ W, const float* __restrict__ bias,
             float* __restrict__ out, int rows, int ntiles)
{
    __shared__ char Ab[64 * 128 * 2];
    const int t = threadIdx.x, wave = t >> 6, lane = t & 63;
    const int lrow = lane & 15, lko = (lane >> 4) * 8, lko2 = lko * 2;

    bf16x8 bfrag[4][4];
#pragma unroll
    for (int f = 0; f < 4; ++f)
#pragma unroll
        for (int ks = 0; ks < 4; ++ks) {
            const float* wp = W + (f * 16 + lrow) * 128 + ks * 32 + lko;
            bf16x8 v;
#pragma unroll
            for (int i = 0; i < 8; ++i) ((unsigned short*)&v)[i] = f2bf(wp[i]);
            bfrag[f][ks] = v;
        }
    float bia[4];
#pragma unroll
    for (int f = 0; f < 4; ++f) bia[f] = bias[f * 16 + lrow];

    const int el = t >> 2, q = t & 3, swz_w = (el & 7) << 4;

    for (int tile = blockIdx.x; tile < ntiles; tile += gridDim.x) {
        __syncthreads();
        {
            const long long e = (long long)tile * 64 + el;
            const bool ok = e < (long long)rows;
            long long arow = 0;
            if (ok) arow = gidx ? (long long)gidx[e] : e;
            const float* ap = A  + arow * 64;
            const float* bp = B2 + e * 64;
#pragma unroll
            for (int i = 0; i < 8; ++i) {
                const int c = q + 4 * i;
                float4 v = make_float4(0.f, 0.f, 0.f, 0.f);
                if (ok) v = (c < 16) ? *(const float4*)(ap + c * 4)
                                     : *(const float4*)(bp + (c - 16) * 4);
                unsigned lo32 = (unsigned)f2bf(v.x) | ((unsigned)f2bf(v.y) << 16);
                unsigned hi32 = (unsigned)f2bf(v.z) | ((unsigned)f2bf(v.w) << 16);
                *(uint2*)(Ab + ((el * 256 + c * 8) ^ swz_w)) = make_uint2(lo32, hi32);
            }
        }
        __syncthreads();

        f32x4 acc[4] = {{0,0,0,0},{0,0,0,0},{0,0,0,0},{0,0,0,0}};
        const int arl = wave * 16 + lrow, rbase = arl * 256, swz_r = (arl & 7) << 4;
#pragma unroll
        for (int ks = 0; ks < 4; ++ks) {
            bf16x8 a = *(const bf16x8*)(Ab + ((rbase + ks * 64 + lko2) ^ swz_r));
#pragma unroll
            for (int f = 0; f < 4; ++f)
                acc[f] = __builtin_amdgcn_mfma_f32_16x16x32_bf16(a, bfrag[f][ks], acc[f], 0, 0, 0);
        }

        const long long erow0 = (long long)tile * 64 + wave * 16 + (lane >> 4) * 4;
#pragma unroll
        for (int r = 0; r < 4; ++r) {
            const long long e = erow0 + r;
            if (e < (long long)rows) {
                if (sidx) {
                    const long long d = (long long)sidx[e] * 64;
#pragma unroll
                    for (int f = 0; f < 4; ++f)
                        atomicAdd(out + d + f * 16 + lrow, fmaxf(acc[f][r] + bia[f], 0.f));
                } else {
                    const long long o = e * 64;
#pragma unroll
                    for (int f = 0; f < 4; ++f)
                        out[o + f * 16 + lrow] = fmaxf(acc[f][r] + bia[f], 0.f);
                }
            }
        }
    }
}

extern "C" void kernel_launch(void* const* d_in, const int* in_sizes, int n_in,
                              void* d_out, int out_size, void* d_ws, size_t ws_size,
                              hipStream_t stream)
{
    const float* H   = (const float*)d_in[0];
    const float* Xe  = (const float*)d_in[1];
    const int*   idx = (const int*)d_in[2];
    const float* M_W = (const float*)d_in[3];
    const float* M_b = (const float*)d_in[4];
    const float* U_W = (const float*)d_in[5];
    const float* U_b = (const float*)d_in[6];
    float* Hn = (float*)d_out;

    const int n_nodes = out_size / 64;
    const int n_edges = in_sizes[1] / 64;
    const int* src = idx;
    const int* dst = idx + n_edges;

    char* ws = (char*)d_ws;
    float* Z = (float*)ws;
    size_t off = (size_t)n_nodes * 64 * sizeof(float);
    unsigned* counts = (unsigned*)(ws + off); off += (size_t)n_nodes * 4;
    unsigned* cursor = (unsigned*)(ws + off); off += (size_t)n_nodes * 4;
    unsigned* pos    = (unsigned*)(ws + off); off += (size_t)n_edges * 4;
    unsigned short* Y = (unsigned short*)(ws + off); off += (size_t)n_edges * 64 * 2;
    const size_t need = off;

    if (ws_size >= need) {
        hipMemsetAsync(counts, 0, (size_t)n_nodes * 4, stream);
        hist_k<<<1024, 256, 0, stream>>>(dst, counts, n_edges);
        scan_k<<<1, 1024, 0, stream>>>(counts, cursor, n_nodes);
        scatter_k<<<1024, 256, 0, stream>>>(dst, cursor, pos, n_edges);
        edge_mlp<<<4096, 256, 0, stream>>>(H, Xe, src, pos, M_W, M_b, Y, n_edges);
        seg_reduce<<<(n_nodes + 3) / 4, 256, 0, stream>>>(Y, counts, cursor, Z, n_nodes);
    } else {
        // fallback: R1 atomic path
        hipMemsetAsync(Z, 0, (size_t)n_nodes * 64 * sizeof(float), stream);
        const int etiles = (n_edges + 63) / 64;
        gnn_mlp<<<2048, 256, 0, stream>>>(H, Xe, src, dst, M_W, M_b, Z, n_edges, etiles);
    }

    const int ntiles = (n_nodes + 63) / 64;
    gnn_mlp<<<ntiles, 256, 0, stream>>>(H, Z, nullptr, nullptr, U_W, U_b, Hn, n_nodes, ntiles);
}

// Round 6
// 434.509 us; speedup vs baseline: 1.1864x; 1.1864x over previous
//
#include <hip/hip_runtime.h>

typedef __attribute__((ext_vector_type(8))) short bf16x8;
typedef __attribute__((ext_vector_type(4))) float f32x4;

// RNE float -> bf16
__device__ __forceinline__ unsigned short f2bf(float f) {
    union { float f; unsigned int u; } v; v.f = f;
    unsigned int r = v.u + 0x7FFFu + ((v.u >> 16) & 1u);
    return (unsigned short)(r >> 16);
}
// packed RNE cvt: low16 = bf16(lo), high16 = bf16(hi)
__device__ __forceinline__ unsigned cvt_pk_bf16(float lo, float hi) {
    unsigned r;
    asm("v_cvt_pk_bf16_f32 %0, %1, %2" : "=v"(r) : "v"(lo), "v"(hi));
    return r;
}

// ---------------- prep kernels ----------------
__global__ void cvt_h(const float* __restrict__ H, unsigned short* __restrict__ Hb, int n8) {
    int i = blockIdx.x * blockDim.x + threadIdx.x;
    if (i >= n8) return;
    const float* p = H + (long long)i * 8;
    float4 a = *(const float4*)p, b = *(const float4*)(p + 4);
    uint4 o;
    o.x = cvt_pk_bf16(a.x, a.y); o.y = cvt_pk_bf16(a.z, a.w);
    o.z = cvt_pk_bf16(b.x, b.y); o.w = cvt_pk_bf16(b.z, b.w);
    *(uint4*)(Hb + (long long)i * 8) = o;
}

__global__ void hist_k(const int* __restrict__ dst, unsigned* __restrict__ counts, int E) {
    for (int i = blockIdx.x * blockDim.x + threadIdx.x; i < E; i += gridDim.x * blockDim.x)
        atomicAdd(&counts[dst[i]], 1u);
}

__global__ __launch_bounds__(1024)
void scan_k(const unsigned* __restrict__ counts, unsigned* __restrict__ cursor, int N) {
    __shared__ unsigned part[1024];
    const int t = threadIdx.x;
    const int chunk = (N + 1023) >> 10;
    const int lo = t * chunk, hi = min(lo + chunk, N);
    unsigned s = 0;
    for (int i = lo; i < hi; ++i) s += counts[i];
    part[t] = s;
    __syncthreads();
    for (int off = 1; off < 1024; off <<= 1) {
        unsigned v = (t >= off) ? part[t - off] : 0u;
        __syncthreads();
        part[t] += v;
        __syncthreads();
    }
    unsigned run = t ? part[t - 1] : 0u;
    for (int i = lo; i < hi; ++i) { cursor[i] = run; run += counts[i]; }
}

// pack (edge id, src, dst) per sorted position: ONE 16B random write / edge
__global__ void scatter_k(const int* __restrict__ src, const int* __restrict__ dst,
                          unsigned* __restrict__ cursor, int4* __restrict__ ep, int E) {
    for (int i = blockIdx.x * blockDim.x + threadIdx.x; i < E; i += gridDim.x * blockDim.x) {
        int d = dst[i];
        unsigned p = atomicAdd(&cursor[d], 1u);
        ep[p] = make_int4(i, src[i], d, 0);
    }
}

// ------- fused edge MLP + wave-local segmented reduce, 3-deep pipeline, 0 barriers -------
// One wave = 16 dst-sorted edges. Swapped MFMA: lane kc*16+lrow holds edge lrow,
// features f*16 + kc*4 + r. Segmented suffix-scan across lrow via shfl_down
// (sorted => dst[i+d]==dst[i] is a run test); run-leader lanes atomicAdd into Z.
__global__ __launch_bounds__(256)
void edge_fused(const unsigned short* __restrict__ Hb, const float* __restrict__ Xe,
                const int4* __restrict__ ep,
                const float* __restrict__ W, const float* __restrict__ bias,
                float* __restrict__ Z, long long E)
{
    const int t = threadIdx.x, lane = t & 63;
    const int lrow = lane & 15, kc = lane >> 4, lko = kc * 8, fo = kc * 4;
    long long g = ((long long)blockIdx.x * blockDim.x + t) >> 6;
    const long long nw = ((long long)gridDim.x * blockDim.x) >> 6;
    const long long ngrp = (E + 15) >> 4;
    if (g >= ngrp) return;                  // no barriers in this kernel

    // W fragments (A-operand): lane holds W[f*16+lrow][ks*32+lko+i]
    bf16x8 wfrag[4][4];
#pragma unroll
    for (int f = 0; f < 4; ++f)
#pragma unroll
        for (int ks = 0; ks < 4; ++ks) {
            const float* wp = W + (f * 16 + lrow) * 128 + ks * 32 + lko;
            bf16x8 v;
#pragma unroll
            for (int i = 0; i < 8; ++i) ((unsigned short*)&v)[i] = f2bf(wp[i]);
            wfrag[f][ks] = v;
        }
    f32x4 bia[4];
#pragma unroll
    for (int f = 0; f < 4; ++f) bia[f] = *(const f32x4*)(bias + f * 16 + fo);

    // ---------- warmup: idx(g), data(g), idx(g+1) ----------
    long long p = g * 16 + lrow;
    int4 ei = (p < E) ? ep[p] : make_int4(0, 0, -1, 0);
    bf16x8 hc0 = {0,0,0,0,0,0,0,0}, hc1 = {0,0,0,0,0,0,0,0};
    float4 xc0 = make_float4(0,0,0,0), xc1 = xc0, xc2 = xc0, xc3 = xc0;
    if (ei.z >= 0) {
        const unsigned short* hp = Hb + (long long)ei.y * 64;
        const float* xp = Xe + (long long)ei.x * 64;
        hc0 = *(const bf16x8*)(hp + lko);  hc1 = *(const bf16x8*)(hp + 32 + lko);
        xc0 = *(const float4*)(xp + lko);      xc1 = *(const float4*)(xp + lko + 4);
        xc2 = *(const float4*)(xp + 32 + lko); xc3 = *(const float4*)(xp + 32 + lko + 4);
    }
    int dcur = ei.z;
    long long p1 = p + nw * 16;
    int4 en = (p1 < E) ? ep[p1] : make_int4(0, 0, -1, 0);

    while (true) {
        // ---- issue data(g+1) loads (indices landed last iteration) ----
        bf16x8 hn0 = {0,0,0,0,0,0,0,0}, hn1 = {0,0,0,0,0,0,0,0};
        float4 xn0 = make_float4(0,0,0,0), xn1 = xn0, xn2 = xn0, xn3 = xn0;
        if (en.z >= 0) {
            const unsigned short* hp = Hb + (long long)en.y * 64;
            const float* xp = Xe + (long long)en.x * 64;
            hn0 = *(const bf16x8*)(hp + lko);  hn1 = *(const bf16x8*)(hp + 32 + lko);
            xn0 = *(const float4*)(xp + lko);      xn1 = *(const float4*)(xp + lko + 4);
            xn2 = *(const float4*)(xp + 32 + lko); xn3 = *(const float4*)(xp + 32 + lko + 4);
        }
        // ---- issue idx(g+2) ----
        const long long p2 = p + 2 * nw * 16;
        int4 e2 = (p2 < E) ? ep[p2] : make_int4(0, 0, -1, 0);

        // ---- compute group g ----
        bf16x8 dfrag[4];
        dfrag[0] = hc0; dfrag[1] = hc1;
        {
            union { unsigned u[4]; bf16x8 v; } c2, c3;
            c2.u[0] = cvt_pk_bf16(xc0.x, xc0.y); c2.u[1] = cvt_pk_bf16(xc0.z, xc0.w);
            c2.u[2] = cvt_pk_bf16(xc1.x, xc1.y); c2.u[3] = cvt_pk_bf16(xc1.z, xc1.w);
            c3.u[0] = cvt_pk_bf16(xc2.x, xc2.y); c3.u[1] = cvt_pk_bf16(xc2.z, xc2.w);
            c3.u[2] = cvt_pk_bf16(xc3.x, xc3.y); c3.u[3] = cvt_pk_bf16(xc3.z, xc3.w);
            dfrag[2] = c2.v; dfrag[3] = c3.v;
        }
        f32x4 acc[4] = {{0,0,0,0},{0,0,0,0},{0,0,0,0},{0,0,0,0}};
#pragma unroll
        for (int ks = 0; ks < 4; ++ks)
#pragma unroll
            for (int f = 0; f < 4; ++f)
                acc[f] = __builtin_amdgcn_mfma_f32_16x16x32_bf16(wfrag[f][ks], dfrag[ks], acc[f], 0, 0, 0);

        f32x4 y[4];
#pragma unroll
        for (int f = 0; f < 4; ++f)
#pragma unroll
            for (int r = 0; r < 4; ++r)
                y[f][r] = fmaxf(acc[f][r] + bia[f][r], 0.f);

        // ---- segmented suffix-sum across the 16 edges (width-16 shuffles) ----
        const int dv = dcur;
#pragma unroll
        for (int d = 1; d < 16; d <<= 1) {
            const int od = __shfl_down(dv, d, 16);
            const bool take = (lrow + d < 16) && (od == dv);
#pragma unroll
            for (int f = 0; f < 4; ++f) {
                f32x4 ty;
#pragma unroll
                for (int r = 0; r < 4; ++r) ty[r] = __shfl_down(y[f][r], d, 16);
                if (take) y[f] += ty;
            }
        }
        const int dprev = __shfl_up(dv, 1, 16);
        if (dv >= 0 && (lrow == 0 || dprev != dv)) {
            float* zp = Z + (long long)dv * 64 + fo;
#pragma unroll
            for (int f = 0; f < 4; ++f)
#pragma unroll
                for (int r = 0; r < 4; ++r)
                    atomicAdd(zp + f * 16 + r, y[f][r]);
        }

        // ---- rotate ----
        g += nw;
        if (g >= ngrp) break;
        p += nw * 16;
        hc0 = hn0; hc1 = hn1; xc0 = xn0; xc1 = xn1; xc2 = xn2; xc3 = xn3;
        dcur = en.z; en = e2;
    }
}

// ------------- generic tiled MLP (R1, known-good): node pass + fallback -------------
__global__ __launch_bounds__(256)
void gnn_mlp(const float* __restrict__ A, const float* __restrict__ B2,
             const int* __restrict__ gidx, const int* __restrict__ sidx,
             const float* __restrict__ W, const float* __restrict__ bias,
             float* __restrict__ out, int rows, int ntiles)
{
    __shared__ char Ab[64 * 128 * 2];
    const int t = threadIdx.x, wave = t >> 6, lane = t & 63;
    const int lrow = lane & 15, lko = (lane >> 4) * 8, lko2 = lko * 2;

    bf16x8 bfrag[4][4];
#pragma unroll
    for (int f = 0; f < 4; ++f)
#pragma unroll
        for (int ks = 0; ks < 4; ++ks) {
            const float* wp = W + (f * 16 + lrow) * 128 + ks * 32 + lko;
            bf16x8 v;
#pragma unroll
            for (int i = 0; i < 8; ++i) ((unsigned short*)&v)[i] = f2bf(wp[i]);
            bfrag[f][ks] = v;
        }
    float bia[4];
#pragma unroll
    for (int f = 0; f < 4; ++f) bia[f] = bias[f * 16 + lrow];

    const int el = t >> 2, q = t & 3, swz_w = (el & 7) << 4;

    for (int tile = blockIdx.x; tile < ntiles; tile += gridDim.x) {
        __syncthreads();
        {
            const long long e = (long long)tile * 64 + el;
            const bool ok = e < (long long)rows;
            long long arow = 0;
            if (ok) arow = gidx ? (long long)gidx[e] : e;
            const float* ap = A  + arow * 64;
            const float* bp = B2 + e * 64;
#pragma unroll
            for (int i = 0; i < 8; ++i) {
                const int c = q + 4 * i;
                float4 v = make_float4(0.f, 0.f, 0.f, 0.f);
                if (ok) v = (c < 16) ? *(const float4*)(ap + c * 4)
                                     : *(const float4*)(bp + (c - 16) * 4);
                unsigned lo32 = (unsigned)f2bf(v.x) | ((unsigned)f2bf(v.y) << 16);
                unsigned hi32 = (unsigned)f2bf(v.z) | ((unsigned)f2bf(v.w) << 16);
                *(uint2*)(Ab + ((el * 256 + c * 8) ^ swz_w)) = make_uint2(lo32, hi32);
            }
        }
        __syncthreads();

        f32x4 acc[4] = {{0,0,0,0},{0,0,0,0},{0,0,0,0},{0,0,0,0}};
        const int arl = wave * 16 + lrow, rbase = arl * 256, swz_r = (arl & 7) << 4;
#pragma unroll
        for (int ks = 0; ks < 4; ++ks) {
            bf16x8 a = *(const bf16x8*)(Ab + ((rbase + ks * 64 + lko2) ^ swz_r));
#pragma unroll
            for (int f = 0; f < 4; ++f)
                acc[f] = __builtin_amdgcn_mfma_f32_16x16x32_bf16(a, bfrag[f][ks], acc[f], 0, 0, 0);
        }

        const long long erow0 = (long long)tile * 64 + wave * 16 + (lane >> 4) * 4;
#pragma unroll
        for (int r = 0; r < 4; ++r) {
            const long long e = erow0 + r;
            if (e < (long long)rows) {
                if (sidx) {
                    const long long d = (long long)sidx[e] * 64;
#pragma unroll
                    for (int f = 0; f < 4; ++f)
                        atomicAdd(out + d + f * 16 + lrow, fmaxf(acc[f][r] + bia[f], 0.f));
                } else {
                    const long long o = e * 64;
#pragma unroll
                    for (int f = 0; f < 4; ++f)
                        out[o + f * 16 + lrow] = fmaxf(acc[f][r] + bia[f], 0.f);
                }
            }
        }
    }
}

extern "C" void kernel_launch(void* const* d_in, const int* in_sizes, int n_in,
                              void* d_out, int out_size, void* d_ws, size_t ws_size,
                              hipStream_t stream)
{
    const float* H   = (const float*)d_in[0];
    const float* Xe  = (const float*)d_in[1];
    const int*   idx = (const int*)d_in[2];
    const float* M_W = (const float*)d_in[3];
    const float* M_b = (const float*)d_in[4];
    const float* U_W = (const float*)d_in[5];
    const float* U_b = (const float*)d_in[6];
    float* Hn = (float*)d_out;

    const int n_nodes = out_size / 64;
    const int n_edges = in_sizes[1] / 64;
    const int* src = idx;
    const int* dst = idx + n_edges;

    char* ws = (char*)d_ws;
    float* Z = (float*)ws;
    size_t off = (size_t)n_nodes * 64 * sizeof(float);
    unsigned* counts = (unsigned*)(ws + off); off += (size_t)n_nodes * 4;
    unsigned* cursor = (unsigned*)(ws + off); off += (size_t)n_nodes * 4;
    int4* epack = (int4*)(ws + off);          off += (size_t)n_edges * 16;
    unsigned short* Hb = (unsigned short*)(ws + off); off += (size_t)n_nodes * 64 * 2;
    const size_t need = off;

    hipMemsetAsync(Z, 0, (size_t)n_nodes * 64 * sizeof(float), stream);

    if (ws_size >= need) {
        hipMemsetAsync(counts, 0, (size_t)n_nodes * 4, stream);
        const int n8 = n_nodes * 8;   // groups of 8 floats in H
        cvt_h<<<(n8 + 255) / 256, 256, 0, stream>>>(H, Hb, n8);
        hist_k<<<1024, 256, 0, stream>>>(dst, counts, n_edges);
        scan_k<<<1, 1024, 0, stream>>>(counts, cursor, n_nodes);
        scatter_k<<<1024, 256, 0, stream>>>(src, dst, cursor, epack, n_edges);
        edge_fused<<<2048, 256, 0, stream>>>(Hb, Xe, epack, M_W, M_b, Z, (long long)n_edges);
    } else {
        const int etiles = (n_edges + 63) / 64;
        gnn_mlp<<<2048, 256, 0, stream>>>(H, Xe, src, dst, M_W, M_b, Z, n_edges, etiles);
    }

    const int ntiles = (n_nodes + 63) / 64;
    gnn_mlp<<<ntiles, 256, 0, stream>>>(H, Z, nullptr, nullptr, U_W, U_b, Hn, n_nodes, ntiles);
}

// Round 7
// 432.891 us; speedup vs baseline: 1.1908x; 1.0037x over previous
//
#include <hip/hip_runtime.h>

typedef __attribute__((ext_vector_type(8))) short bf16x8;
typedef __attribute__((ext_vector_type(4))) float f32x4;

// RNE float -> bf16
__device__ __forceinline__ unsigned short f2bf(float f) {
    union { float f; unsigned int u; } v; v.f = f;
    unsigned int r = v.u + 0x7FFFu + ((v.u >> 16) & 1u);
    return (unsigned short)(r >> 16);
}
// packed RNE cvt: low16 = bf16(lo), high16 = bf16(hi)
__device__ __forceinline__ unsigned cvt_pk_bf16(float lo, float hi) {
    unsigned r;
    asm("v_cvt_pk_bf16_f32 %0, %1, %2" : "=v"(r) : "v"(lo), "v"(hi));
    return r;
}

// ---------------- custom zero (hipMemsetAsync fills ran at ~69 GB/s in-graph) ----------------
__global__ void zero_k(unsigned* __restrict__ p, long long nw) {
    long long i = ((long long)blockIdx.x * blockDim.x + threadIdx.x) * 4;
    const long long st = (long long)gridDim.x * blockDim.x * 4;
    for (; i + 4 <= nw; i += st) *(uint4*)(p + i) = make_uint4(0, 0, 0, 0);
    for (; i < nw; ++i) p[i] = 0u;
}

// ---------------- prep kernels ----------------
__global__ void cvt_h(const float* __restrict__ H, unsigned short* __restrict__ Hb, int n8) {
    int i = blockIdx.x * blockDim.x + threadIdx.x;
    if (i >= n8) return;
    const float* p = H + (long long)i * 8;
    float4 a = *(const float4*)p, b = *(const float4*)(p + 4);
    uint4 o;
    o.x = cvt_pk_bf16(a.x, a.y); o.y = cvt_pk_bf16(a.z, a.w);
    o.z = cvt_pk_bf16(b.x, b.y); o.w = cvt_pk_bf16(b.z, b.w);
    *(uint4*)(Hb + (long long)i * 8) = o;
}

__global__ void hist_k(const int* __restrict__ dst, unsigned* __restrict__ counts, int E) {
    for (int i = blockIdx.x * blockDim.x + threadIdx.x; i < E; i += gridDim.x * blockDim.x)
        atomicAdd(&counts[dst[i]], 1u);
}

__global__ __launch_bounds__(1024)
void scan_k(const unsigned* __restrict__ counts, unsigned* __restrict__ cursor, int N) {
    __shared__ unsigned part[1024];
    const int t = threadIdx.x;
    const int chunk = (N + 1023) >> 10;
    const int lo = t * chunk, hi = min(lo + chunk, N);
    unsigned s = 0;
    for (int i = lo; i < hi; ++i) s += counts[i];
    part[t] = s;
    __syncthreads();
    for (int off = 1; off < 1024; off <<= 1) {
        unsigned v = (t >= off) ? part[t - off] : 0u;
        __syncthreads();
        part[t] += v;
        __syncthreads();
    }
    unsigned run = t ? part[t - 1] : 0u;
    for (int i = lo; i < hi; ++i) { cursor[i] = run; run += counts[i]; }
}

// pack (edge id, src, dst) per sorted position: ONE 16B random write / edge
__global__ void scatter_k(const int* __restrict__ src, const int* __restrict__ dst,
                          unsigned* __restrict__ cursor, int4* __restrict__ ep, int E) {
    for (int i = blockIdx.x * blockDim.x + threadIdx.x; i < E; i += gridDim.x * blockDim.x) {
        int d = dst[i];
        unsigned p = atomicAdd(&cursor[d], 1u);
        ep[p] = make_int4(i, src[i], d, 0);
    }
}

// ------- fused edge MLP + wave-local segmented reduce, 3-deep pipeline, 0 barriers -------
// One wave = 16 dst-sorted edges. Swapped MFMA: lane kc*16+lrow holds edge lrow,
// features f*16 + kc*4 + r. Segmented suffix-scan across lrow via shfl_down
// (sorted => dst[i+d]==dst[i] is a run test); run-leader lanes atomicAdd into Z.
__global__ __launch_bounds__(256)
void edge_fused(const unsigned short* __restrict__ Hb, const float* __restrict__ Xe,
                const int4* __restrict__ ep,
                const float* __restrict__ W, const float* __restrict__ bias,
                float* __restrict__ Z, long long E)
{
    const int t = threadIdx.x, lane = t & 63;
    const int lrow = lane & 15, kc = lane >> 4, lko = kc * 8, fo = kc * 4;
    long long g = ((long long)blockIdx.x * blockDim.x + t) >> 6;
    const long long nw = ((long long)gridDim.x * blockDim.x) >> 6;
    const long long ngrp = (E + 15) >> 4;
    if (g >= ngrp) return;                  // no barriers in this kernel

    // W fragments (A-operand): lane holds W[f*16+lrow][ks*32+lko+i]
    bf16x8 wfrag[4][4];
#pragma unroll
    for (int f = 0; f < 4; ++f)
#pragma unroll
        for (int ks = 0; ks < 4; ++ks) {
            const float* wp = W + (f * 16 + lrow) * 128 + ks * 32 + lko;
            bf16x8 v;
#pragma unroll
            for (int i = 0; i < 8; ++i) ((unsigned short*)&v)[i] = f2bf(wp[i]);
            wfrag[f][ks] = v;
        }
    f32x4 bia[4];
#pragma unroll
    for (int f = 0; f < 4; ++f) bia[f] = *(const f32x4*)(bias + f * 16 + fo);

    // ---------- warmup: idx(g), data(g), idx(g+1) ----------
    long long p = g * 16 + lrow;
    int4 ei = (p < E) ? ep[p] : make_int4(0, 0, -1, 0);
    bf16x8 hc0 = {0,0,0,0,0,0,0,0}, hc1 = {0,0,0,0,0,0,0,0};
    float4 xc0 = make_float4(0,0,0,0), xc1 = xc0, xc2 = xc0, xc3 = xc0;
    if (ei.z >= 0) {
        const unsigned short* hp = Hb + (long long)ei.y * 64;
        const float* xp = Xe + (long long)ei.x * 64;
        hc0 = *(const bf16x8*)(hp + lko);  hc1 = *(const bf16x8*)(hp + 32 + lko);
        xc0 = *(const float4*)(xp + lko);      xc1 = *(const float4*)(xp + lko + 4);
        xc2 = *(const float4*)(xp + 32 + lko); xc3 = *(const float4*)(xp + 32 + lko + 4);
    }
    int dcur = ei.z;
    long long p1 = p + nw * 16;
    int4 en = (p1 < E) ? ep[p1] : make_int4(0, 0, -1, 0);

    while (true) {
        // ---- issue data(g+1) loads (indices landed last iteration) ----
        bf16x8 hn0 = {0,0,0,0,0,0,0,0}, hn1 = {0,0,0,0,0,0,0,0};
        float4 xn0 = make_float4(0,0,0,0), xn1 = xn0, xn2 = xn0, xn3 = xn0;
        if (en.z >= 0) {
            const unsigned short* hp = Hb + (long long)en.y * 64;
            const float* xp = Xe + (long long)en.x * 64;
            hn0 = *(const bf16x8*)(hp + lko);  hn1 = *(const bf16x8*)(hp + 32 + lko);
            xn0 = *(const float4*)(xp + lko);      xn1 = *(const float4*)(xp + lko + 4);
            xn2 = *(const float4*)(xp + 32 + lko); xn3 = *(const float4*)(xp + 32 + lko + 4);
        }
        // ---- issue idx(g+2) ----
        const long long p2 = p + 2 * nw * 16;
        int4 e2 = (p2 < E) ? ep[p2] : make_int4(0, 0, -1, 0);

        // ---- compute group g ----
        bf16x8 dfrag[4];
        dfrag[0] = hc0; dfrag[1] = hc1;
        {
            union { unsigned u[4]; bf16x8 v; } c2, c3;
            c2.u[0] = cvt_pk_bf16(xc0.x, xc0.y); c2.u[1] = cvt_pk_bf16(xc0.z, xc0.w);
            c2.u[2] = cvt_pk_bf16(xc1.x, xc1.y); c2.u[3] = cvt_pk_bf16(xc1.z, xc1.w);
            c3.u[0] = cvt_pk_bf16(xc2.x, xc2.y); c3.u[1] = cvt_pk_bf16(xc2.z, xc2.w);
            c3.u[2] = cvt_pk_bf16(xc3.x, xc3.y); c3.u[3] = cvt_pk_bf16(xc3.z, xc3.w);
            dfrag[2] = c2.v; dfrag[3] = c3.v;
        }
        f32x4 acc[4] = {{0,0,0,0},{0,0,0,0},{0,0,0,0},{0,0,0,0}};
#pragma unroll
        for (int ks = 0; ks < 4; ++ks)
#pragma unroll
            for (int f = 0; f < 4; ++f)
                acc[f] = __builtin_amdgcn_mfma_f32_16x16x32_bf16(wfrag[f][ks], dfrag[ks], acc[f], 0, 0, 0);

        f32x4 y[4];
#pragma unroll
        for (int f = 0; f < 4; ++f)
#pragma unroll
            for (int r = 0; r < 4; ++r)
                y[f][r] = fmaxf(acc[f][r] + bia[f][r], 0.f);

        // ---- segmented suffix-sum across the 16 edges (width-16 shuffles) ----
        const int dv = dcur;
#pragma unroll
        for (int d = 1; d < 16; d <<= 1) {
            const int od = __shfl_down(dv, d, 16);
            const bool take = (lrow + d < 16) && (od == dv);
#pragma unroll
            for (int f = 0; f < 4; ++f) {
                f32x4 ty;
#pragma unroll
                for (int r = 0; r < 4; ++r) ty[r] = __shfl_down(y[f][r], d, 16);
                if (take) y[f] += ty;
            }
        }
        const int dprev = __shfl_up(dv, 1, 16);
        if (dv >= 0 && (lrow == 0 || dprev != dv)) {
            float* zp = Z + (long long)dv * 64 + fo;
#pragma unroll
            for (int f = 0; f < 4; ++f)
#pragma unroll
                for (int r = 0; r < 4; ++r)
                    atomicAdd(zp + f * 16 + r, y[f][r]);
        }

        // ---- rotate ----
        g += nw;
        if (g >= ngrp) break;
        p += nw * 16;
        hc0 = hn0; hc1 = hn1; xc0 = xn0; xc1 = xn1; xc2 = xn2; xc3 = xn3;
        dcur = en.z; en = e2;
    }
}

// ------------- generic tiled MLP (R1, known-good): node pass + fallback -------------
__global__ __launch_bounds__(256)
void gnn_mlp(const float* __restrict__ A, const float* __restrict__ B2,
             const int* __restrict__ gidx, const int* __restrict__ sidx,
             const float* __restrict__ W, const float* __restrict__ bias,
             float* __restrict__ out, int rows, int ntiles)
{
    __shared__ char Ab[64 * 128 * 2];
    const int t = threadIdx.x, wave = t >> 6, lane = t & 63;
    const int lrow = lane & 15, lko = (lane >> 4) * 8, lko2 = lko * 2;

    bf16x8 bfrag[4][4];
#pragma unroll
    for (int f = 0; f < 4; ++f)
#pragma unroll
        for (int ks = 0; ks < 4; ++ks) {
            const float* wp = W + (f * 16 + lrow) * 128 + ks * 32 + lko;
            bf16x8 v;
#pragma unroll
            for (int i = 0; i < 8; ++i) ((unsigned short*)&v)[i] = f2bf(wp[i]);
            bfrag[f][ks] = v;
        }
    float bia[4];
#pragma unroll
    for (int f = 0; f < 4; ++f) bia[f] = bias[f * 16 + lrow];

    const int el = t >> 2, q = t & 3, swz_w = (el & 7) << 4;

    for (int tile = blockIdx.x; tile < ntiles; tile += gridDim.x) {
        __syncthreads();
        {
            const long long e = (long long)tile * 64 + el;
            const bool ok = e < (long long)rows;
            long long arow = 0;
            if (ok) arow = gidx ? (long long)gidx[e] : e;
            const float* ap = A  + arow * 64;
            const float* bp = B2 + e * 64;
#pragma unroll
            for (int i = 0; i < 8; ++i) {
                const int c = q + 4 * i;
                float4 v = make_float4(0.f, 0.f, 0.f, 0.f);
                if (ok) v = (c < 16) ? *(const float4*)(ap + c * 4)
                                     : *(const float4*)(bp + (c - 16) * 4);
                unsigned lo32 = (unsigned)f2bf(v.x) | ((unsigned)f2bf(v.y) << 16);
                unsigned hi32 = (unsigned)f2bf(v.z) | ((unsigned)f2bf(v.w) << 16);
                *(uint2*)(Ab + ((el * 256 + c * 8) ^ swz_w)) = make_uint2(lo32, hi32);
            }
        }
        __syncthreads();

        f32x4 acc[4] = {{0,0,0,0},{0,0,0,0},{0,0,0,0},{0,0,0,0}};
        const int arl = wave * 16 + lrow, rbase = arl * 256, swz_r = (arl & 7) << 4;
#pragma unroll
        for (int ks = 0; ks < 4; ++ks) {
            bf16x8 a = *(const bf16x8*)(Ab + ((rbase + ks * 64 + lko2) ^ swz_r));
#pragma unroll
            for (int f = 0; f < 4; ++f)
                acc[f] = __builtin_amdgcn_mfma_f32_16x16x32_bf16(a, bfrag[f][ks], acc[f], 0, 0, 0);
        }

        const long long erow0 = (long long)tile * 64 + wave * 16 + (lane >> 4) * 4;
#pragma unroll
        for (int r = 0; r < 4; ++r) {
            const long long e = erow0 + r;
            if (e < (long long)rows) {
                if (sidx) {
                    const long long d = (long long)sidx[e] * 64;
#pragma unroll
                    for (int f = 0; f < 4; ++f)
                        atomicAdd(out + d + f * 16 + lrow, fmaxf(acc[f][r] + bia[f], 0.f));
                } else {
                    const long long o = e * 64;
#pragma unroll
                    for (int f = 0; f < 4; ++f)
                        out[o + f * 16 + lrow] = fmaxf(acc[f][r] + bia[f], 0.f);
                }
            }
        }
    }
}

extern "C" void kernel_launch(void* const* d_in, const int* in_sizes, int n_in,
                              void* d_out, int out_size, void* d_ws, size_t ws_size,
                              hipStream_t stream)
{
    const float* H   = (const float*)d_in[0];
    const float* Xe  = (const float*)d_in[1];
    const int*   idx = (const int*)d_in[2];
    const float* M_W = (const float*)d_in[3];
    const float* M_b = (const float*)d_in[4];
    const float* U_W = (const float*)d_in[5];
    const float* U_b = (const float*)d_in[6];
    float* Hn = (float*)d_out;

    const int n_nodes = out_size / 64;
    const int n_edges = in_sizes[1] / 64;
    const int* src = idx;
    const int* dst = idx + n_edges;

    char* ws = (char*)d_ws;
    float* Z = (float*)ws;                     // [N,64] fp32
    size_t off = (size_t)n_nodes * 64 * sizeof(float);
    unsigned* counts = (unsigned*)(ws + off); off += (size_t)n_nodes * 4;   // adjacent to Z
    unsigned* cursor = (unsigned*)(ws + off); off += (size_t)n_nodes * 4;
    int4* epack = (int4*)(ws + off);          off += (size_t)n_edges * 16;
    unsigned short* Hb = (unsigned short*)(ws + off); off += (size_t)n_nodes * 64 * 2;
    const size_t need = off;

    if (ws_size >= need) {
        // zero Z + counts (contiguous) with a real store kernel — hipMemsetAsync
        // fills ran at ~69 GB/s inside the captured graph (R6 profile).
        const long long zwords = (long long)n_nodes * 65;   // 64 floats + 1 uint per node
        zero_k<<<2048, 256, 0, stream>>>((unsigned*)Z, zwords);
        const int n8 = n_nodes * 8;   // groups of 8 floats in H
        cvt_h<<<(n8 + 255) / 256, 256, 0, stream>>>(H, Hb, n8);
        hist_k<<<1024, 256, 0, stream>>>(dst, counts, n_edges);
        scan_k<<<1, 1024, 0, stream>>>(counts, cursor, n_nodes);
        scatter_k<<<1024, 256, 0, stream>>>(src, dst, cursor, epack, n_edges);
        edge_fused<<<2048, 256, 0, stream>>>(Hb, Xe, epack, M_W, M_b, Z, (long long)n_edges);
    } else {
        const long long zwords = (long long)n_nodes * 64;
        zero_k<<<2048, 256, 0, stream>>>((unsigned*)Z, zwords);
        const int etiles = (n_edges + 63) / 64;
        gnn_mlp<<<2048, 256, 0, stream>>>(H, Xe, src, dst, M_W, M_b, Z, n_edges, etiles);
    }

    const int ntiles = (n_nodes + 63) / 64;
    gnn_mlp<<<ntiles, 256, 0, stream>>>(H, Z, nullptr, nullptr, U_W, U_b, Hn, n_nodes, ntiles);
}